// Round 4
// baseline (60.713 us; speedup 1.0000x reference)
//
#include <hip/hip_runtime.h>

typedef __attribute__((ext_vector_type(8))) short short8;
typedef __attribute__((ext_vector_type(4))) short short4v;
typedef __attribute__((ext_vector_type(4))) float f32x4;

// 3-stage RK matched to Euler-120 (h=1/1200, H=0.1) through order 3 (see R2/R3).
#define RA21 ((float)(1.0/30.0))
#define RA32 ((float)(9401.0/140420.0))
#define RB2  ((float)(119.0/48000.0))
#define RB3  ((float)(49294441.0/676872000.0))
#define RB1  ((float)(0.1 - 119.0/48000.0 - 49294441.0/676872000.0))

static __device__ __forceinline__ short bf16rne(float f) {
    unsigned u = __builtin_bit_cast(unsigned, f);
    u += 0x7FFFu + ((u >> 16) & 1u);
    return (short)(u >> 16);
}
static __device__ __forceinline__ float bf16f(short h) {
    unsigned u = ((unsigned)(unsigned short)h) << 16;
    return __builtin_bit_cast(float, u);
}
static __device__ __forceinline__ float fast_tanh(float x) {
    float t = __builtin_amdgcn_exp2f(x * 2.88539008177792681f);
    float r = __builtin_amdgcn_rcpf(t + 1.0f);
    return __builtin_fmaf(-2.0f, r, 1.0f);
}

// LDS-only barrier: no vmcnt drain, so checkpoint stores retire in the shadow.
#define BARRIER() asm volatile("s_waitcnt lgkmcnt(0)\n\ts_barrier" ::: "memory")

// 64 WGs x 512 threads (8 waves, 2/SIMD). WG owns 16 data rows.
// State u = y*W1 + b1 (256-dim, 32 cols/wave, 8 f32/lane) maintained in regs.
// Per RK stage: h=tanh(u) -> LDS -> ONE fused GEMM h*W12 (W12 = W2*W1, bf16,
// A-frags in regs). y updated once per macro step via hc*W2.
// mfma_f32_16x16x32_bf16: A: lane l holds A[l&15][(l>>4)*8+j]
//                         B: lane l holds B[(l>>4)*8+j][l&15]
//                         C: lane l holds C[(l>>4)*4+i][l&15]
__global__ __launch_bounds__(512, 1)
void ode_kernel(const float* __restrict__ z0,  const float* __restrict__ dis,
                const float* __restrict__ W1,  const float* __restrict__ b1,
                const float* __restrict__ W2,  const float* __restrict__ b2,
                float* __restrict__ out, short* wsp)
{
    const int tid = threadIdx.x;
    const int wv  = tid >> 6;
    const int l   = tid & 63;
    const int lr  = l & 15;
    const int lg  = l >> 4;
    const int swz = (lr & 7) << 3;          // element-index XOR for [row][256] tiles
    const int r   = blockIdx.x * 16 + lr;
    const int bb  = r >> 7;
    const int nn  = r & 127;

    __shared__ union {
        short w2s[128 * 128];               // [k 128][m 128] bf16, swizzled (prologue)
        float r1s[256];                     // r1 broadcast (prologue)
        struct { short xb[16 * 256]; short hb[3][16 * 256]; } mm;  // main loop (32 KiB)
    } lds;

    // ---------- small loads ----------
    const float dis_r = dis[r];
    float yv[4];
#pragma unroll
    for (int i = 0; i < 4; ++i) {
        int col = wv * 16 + lg * 4 + i;
        yv[i] = (col == 127) ? dis_r : z0[r * 127 + col];
    }
    float b1v[2][4];
#pragma unroll
    for (int nt = 0; nt < 2; ++nt)
#pragma unroll
      for (int i = 0; i < 4; ++i) b1v[nt][i] = b1[wv*32 + nt*16 + lg*4 + i];
    float b2v[4];
#pragma unroll
    for (int i = 0; i < 4; ++i) b2v[i] = b2[wv*16 + lg*4 + i];

    // W1^T A-frags for this wave's 32 u-cols (W12 build + t0 GEMM1)
    short8 a1f[2][4];
#pragma unroll
    for (int nt = 0; nt < 2; ++nt)
#pragma unroll
      for (int mt = 0; mt < 4; ++mt) {
        short8 v;
#pragma unroll
        for (int j = 0; j < 8; ++j)
          v[j] = bf16rne(W1[(mt*32 + lg*8 + j)*256 + (wv*32 + nt*16 + lr)]);
        a1f[nt][mt] = v;
      }
    // W2^T A-frags for this wave's 16 y-cols (y-update GEMM)
    short8 a2f[8];
#pragma unroll
    for (int kt = 0; kt < 8; ++kt) {
        short8 v;
#pragma unroll
        for (int j = 0; j < 8; ++j)
          v[j] = bf16rne(W2[(kt*32 + lg*8 + j)*128 + (wv*16 + lr)]);
        a2f[kt] = v;
    }

    // ---------- build W12^T[c][k] = sum_m W1[m][c]*W2[k][m], c in wave's 32 cols ----
#pragma unroll 1
    for (int kh = 0; kh < 2; ++kh) {
        {   // cooperative stage: W2[kh*128 + k][0..128) -> lds.w2s (bf16, swizzled)
            int k  = tid >> 2;
            int m0 = (tid & 3) * 32;
            const float* src = &W2[(size_t)(kh*128 + k)*128 + m0];
            float f[32];
#pragma unroll
            for (int q = 0; q < 8; ++q)
                *reinterpret_cast<f32x4*>(&f[q*4]) =
                    *reinterpret_cast<const f32x4*>(&src[q*4]);
#pragma unroll
            for (int g = 0; g < 4; ++g) {
                short8 v;
#pragma unroll
                for (int j = 0; j < 8; ++j) v[j] = bf16rne(f[g*8 + j]);
                *reinterpret_cast<short8*>((char*)lds.w2s +
                    ((k*256 + m0*2 + g*16) ^ ((k & 7) << 4))) = v;
            }
        }
        __syncthreads();
#pragma unroll 1
        for (int kt = 0; kt < 8; ++kt) {
            f32x4 ac0 = {0.f,0.f,0.f,0.f}, ac1 = {0.f,0.f,0.f,0.f};
#pragma unroll
            for (int mt = 0; mt < 4; ++mt) {
                int kl = kt*16 + lr;
                short8 bf = *reinterpret_cast<const short8*>((const char*)lds.w2s +
                               ((kl*256 + mt*64 + lg*16) ^ ((kl & 7) << 4)));
                ac0 = __builtin_amdgcn_mfma_f32_16x16x32_bf16(a1f[0][mt], bf, ac0, 0,0,0);
                ac1 = __builtin_amdgcn_mfma_f32_16x16x32_bf16(a1f[1][mt], bf, ac1, 0,0,0);
            }
            int k = kh*128 + kt*16 + lr;
#pragma unroll
            for (int i = 0; i < 4; ++i) {
                wsp[(wv*32 +      lg*4 + i)*256 + k] = bf16rne(ac0[i]);
                wsp[(wv*32 + 16 + lg*4 + i)*256 + k] = bf16rne(ac1[i]);
            }
        }
        __syncthreads();   // all w2s reads done before restage / r1s reuse
    }

    // ---------- r1 = b2 * W1 (u-space) via MFMA (B col 0 = b2) ----------
    f32x4 aR0 = {0.f,0.f,0.f,0.f}, aR1 = {0.f,0.f,0.f,0.f};
#pragma unroll
    for (int mt = 0; mt < 4; ++mt) {
        short8 bfr;
#pragma unroll
        for (int j = 0; j < 8; ++j)
            bfr[j] = (lr == 0) ? bf16rne(b2[mt*32 + lg*8 + j]) : (short)0;
        aR0 = __builtin_amdgcn_mfma_f32_16x16x32_bf16(a1f[0][mt], bfr, aR0, 0,0,0);
        aR1 = __builtin_amdgcn_mfma_f32_16x16x32_bf16(a1f[1][mt], bfr, aR1, 0,0,0);
    }
    if (lr == 0) {
#pragma unroll
        for (int i = 0; i < 4; ++i) {
            lds.r1s[wv*32 +      lg*4 + i] = aR0[i];
            lds.r1s[wv*32 + 16 + lg*4 + i] = aR1[i];
        }
    }
    __syncthreads();
    f32x4 r1v[2];
    r1v[0] = *reinterpret_cast<const f32x4*>(&lds.r1s[wv*32 +      lg*4]);
    r1v[1] = *reinterpret_cast<const f32x4*>(&lds.r1s[wv*32 + 16 + lg*4]);

    // W12^T A-frags readback (each wave reads only its own writes)
    short8 a12f[2][8];
#pragma unroll
    for (int nt = 0; nt < 2; ++nt)
#pragma unroll
      for (int kt = 0; kt < 8; ++kt)
        a12f[nt][kt] = *reinterpret_cast<const short8*>(
            &wsp[(wv*32 + nt*16 + lr)*256 + kt*32 + lg*8]);
    __syncthreads();   // r1s region about to be reused as xb

    // ---------- t0: u1 = y W1 + b1 via hi/lo GEMM1 ----------
    {
        short4v hi, lo;
#pragma unroll
        for (int i = 0; i < 4; ++i) {
            short hh = bf16rne(yv[i]);
            hi[i] = hh;
            lo[i] = bf16rne(yv[i] - bf16f(hh));
        }
        int c = wv*16 + lg*4;
        *reinterpret_cast<short4v*>(&lds.mm.xb[(lr*256 + c) ^ swz])       = hi;
        *reinterpret_cast<short4v*>(&lds.mm.xb[(lr*256 + 128 + c) ^ swz]) = lo;
    }
    __syncthreads();
    float u1[2][4];
    {
        short8 xf[8];
#pragma unroll
        for (int kt = 0; kt < 8; ++kt)
            xf[kt] = *reinterpret_cast<const short8*>(
                &lds.mm.xb[(lr*256 + kt*32 + lg*8) ^ swz]);
        f32x4 aA[2], aB[2];
#pragma unroll
        for (int nt = 0; nt < 2; ++nt) {
            f32x4 t0v, zv;
#pragma unroll
            for (int i = 0; i < 4; ++i) { t0v[i] = b1v[nt][i]; zv[i] = 0.f; }
            aA[nt] = t0v; aB[nt] = zv;
        }
#pragma unroll
        for (int kt = 0; kt < 4; ++kt)
#pragma unroll
          for (int nt = 0; nt < 2; ++nt) {
            aA[nt] = __builtin_amdgcn_mfma_f32_16x16x32_bf16(a1f[nt][kt], xf[kt],   aA[nt], 0,0,0);
            aB[nt] = __builtin_amdgcn_mfma_f32_16x16x32_bf16(a1f[nt][kt], xf[kt+4], aB[nt], 0,0,0);
          }
#pragma unroll
        for (int nt = 0; nt < 2; ++nt)
#pragma unroll
          for (int i = 0; i < 4; ++i) u1[nt][i] = aA[nt][i] + aB[nt][i];
    }

    auto checkpoint = [&](int ti) {
        bool msk = ((float)ti / 10.0f) < dis_r;
        f32x4 v;
#pragma unroll
        for (int i = 0; i < 4; ++i) v[i] = msk ? yv[i] : 0.0f;
        *reinterpret_cast<f32x4*>(
            &out[(((size_t)bb*10 + ti)*128 + nn)*128 + wv*16 + lg*4]) = v;
    };
    checkpoint(0);

    auto stage_h = [&](int buf, const float (&h)[2][4]) {
#pragma unroll
        for (int nt = 0; nt < 2; ++nt) {
            short4v hv;
#pragma unroll
            for (int i = 0; i < 4; ++i) hv[i] = bf16rne(h[nt][i]);
            *reinterpret_cast<short4v*>(
                &lds.mm.hb[buf][(lr*256 + wv*32 + nt*16 + lg*4) ^ swz]) = hv;
        }
    };
    auto read_frags = [&](int buf, short8 (&hf)[8]) {
#pragma unroll
        for (int kt = 0; kt < 8; ++kt)
            hf[kt] = *reinterpret_cast<const short8*>(
                &lds.mm.hb[buf][(lr*256 + kt*32 + lg*8) ^ swz]);
    };
    auto w12mm = [&](const short8 (&hf)[8], const f32x4 (&init)[2], float (&g)[2][4]) {
        f32x4 gA[2], gB[2];
#pragma unroll
        for (int nt = 0; nt < 2; ++nt) {
            gA[nt] = init[nt];
            f32x4 z;
#pragma unroll
            for (int i = 0; i < 4; ++i) z[i] = 0.f;
            gB[nt] = z;
        }
#pragma unroll
        for (int kt = 0; kt < 4; ++kt)
#pragma unroll
          for (int nt = 0; nt < 2; ++nt) {
            gA[nt] = __builtin_amdgcn_mfma_f32_16x16x32_bf16(a12f[nt][kt],   hf[kt],   gA[nt], 0,0,0);
            gB[nt] = __builtin_amdgcn_mfma_f32_16x16x32_bf16(a12f[nt][kt+4], hf[kt+4], gB[nt], 0,0,0);
          }
#pragma unroll
        for (int nt = 0; nt < 2; ++nt)
#pragma unroll
          for (int i = 0; i < 4; ++i) g[nt][i] = gA[nt][i] + gB[nt][i];
    };

    // ---------- main loop: 9 macro steps x 3 barrier-phases ----------
#pragma unroll 1
    for (int ms = 0; ms < 9; ++ms) {
        float h1[2][4], h2[2][4], g[2][4], u2[2][4], u3[2][4], hc[2][4];

        // phase A: h1 = tanh(u1); u2 = u1 + A21*(h1*W12 + r1)
#pragma unroll
        for (int nt = 0; nt < 2; ++nt)
#pragma unroll
          for (int i = 0; i < 4; ++i) h1[nt][i] = fast_tanh(u1[nt][i]);
        stage_h(0, h1);
        BARRIER();
        {
            short8 hf[8]; read_frags(0, hf);
            w12mm(hf, r1v, g);
        }
#pragma unroll
        for (int nt = 0; nt < 2; ++nt)
#pragma unroll
          for (int i = 0; i < 4; ++i)
            u2[nt][i] = __builtin_fmaf(RA21, g[nt][i], u1[nt][i]);

        // phase B: h2 = tanh(u2); u3 = u1 + A32*(h2*W12 + r1)
#pragma unroll
        for (int nt = 0; nt < 2; ++nt)
#pragma unroll
          for (int i = 0; i < 4; ++i) h2[nt][i] = fast_tanh(u2[nt][i]);
        stage_h(1, h2);
        BARRIER();
        {
            short8 hf[8]; read_frags(1, hf);
            w12mm(hf, r1v, g);
        }
#pragma unroll
        for (int nt = 0; nt < 2; ++nt)
#pragma unroll
          for (int i = 0; i < 4; ++i)
            u3[nt][i] = __builtin_fmaf(RA32, g[nt][i], u1[nt][i]);

        // phase C: hc = B1 h1 + B2 h2 + B3 tanh(u3);
        //          u1 += hc*W12 + 0.1*r1;  y += hc*W2 + 0.1*b2
#pragma unroll
        for (int nt = 0; nt < 2; ++nt)
#pragma unroll
          for (int i = 0; i < 4; ++i) {
            float h3 = fast_tanh(u3[nt][i]);
            float a = RB1 * h1[nt][i];
            a = __builtin_fmaf(RB2, h2[nt][i], a);
            hc[nt][i] = __builtin_fmaf(RB3, h3, a);
          }
        stage_h(2, hc);
        BARRIER();
        {
            short8 hf[8]; read_frags(2, hf);
            f32x4 initc[2];
#pragma unroll
            for (int nt = 0; nt < 2; ++nt)
#pragma unroll
              for (int i = 0; i < 4; ++i) initc[nt][i] = 0.1f * r1v[nt][i];
            w12mm(hf, initc, g);
#pragma unroll
            for (int nt = 0; nt < 2; ++nt)
#pragma unroll
              for (int i = 0; i < 4; ++i) u1[nt][i] += g[nt][i];

            f32x4 yA, yB;
#pragma unroll
            for (int i = 0; i < 4; ++i) { yA[i] = 0.1f * b2v[i]; yB[i] = 0.f; }
#pragma unroll
            for (int kt = 0; kt < 4; ++kt) {
                yA = __builtin_amdgcn_mfma_f32_16x16x32_bf16(a2f[kt],   hf[kt],   yA, 0,0,0);
                yB = __builtin_amdgcn_mfma_f32_16x16x32_bf16(a2f[kt+4], hf[kt+4], yB, 0,0,0);
            }
#pragma unroll
            for (int i = 0; i < 4; ++i) yv[i] += yA[i] + yB[i];
        }
        checkpoint(ms + 1);
    }
}

extern "C" void kernel_launch(void* const* d_in, const int* in_sizes, int n_in,
                              void* d_out, int out_size, void* d_ws, size_t ws_size,
                              hipStream_t stream) {
    const float* z0  = (const float*)d_in[0];
    const float* dis = (const float*)d_in[1];
    // d_in[2] = t (unused; t_i = i/10 hardcoded per model semantics)
    const float* W1  = (const float*)d_in[3];
    const float* b1  = (const float*)d_in[4];
    const float* W2  = (const float*)d_in[5];
    const float* b2  = (const float*)d_in[6];
    float* out = (float*)d_out;
    short* wsp = (short*)d_ws;   // 256*256 bf16 = 128 KiB for W12^T

    ode_kernel<<<dim3(64), dim3(512), 0, stream>>>(z0, dis, W1, b1, W2, b2, out, wsp);
}